// Round 1
// baseline (210.622 us; speedup 1.0000x reference)
//
#include <hip/hip_runtime.h>
#include <hip/hip_bf16.h>

// NodeAggregator (DiffPool-style) forward on MI355X.
// Key fact: STE makes forward output == degree-normalized `pooled`; top-k is dead code.
// Pipeline: cvt(x,adj,W) -> G1 relu-GEMM -> G2 GEMM -> softmax -> T(S) ->
//           G3 adj@S -> T(mid) -> G4 S^T@mid -> G5 S^T@x -> rowsum+finalize.
// All GEMMs: bf16 MFMA 16x16x32, A row-major + B^T row-major, global_load_lds staging.

typedef float f32x4 __attribute__((ext_vector_type(4)));
typedef __bf16 bf16x8 __attribute__((ext_vector_type(8)));

__device__ __forceinline__ void async_load16(const void* g, void* l) {
  __builtin_amdgcn_global_load_lds((const __attribute__((address_space(1))) void*)g,
                                   (__attribute__((address_space(3))) void*)l, 16, 0, 0);
}

__device__ __forceinline__ unsigned short f2bf_bits(float f) {
  return __builtin_bit_cast(unsigned short, (__bf16)f);
}

// ---------------- converts ----------------
__global__ __launch_bounds__(256) void cvt_f32_bf16_k(const float* __restrict__ in,
                                                      __bf16* __restrict__ out,
                                                      long long n4) {
  long long i = blockIdx.x * 256LL + threadIdx.x;
  const long long stride = (long long)gridDim.x * 256LL;
  for (; i < n4; i += stride) {
    const float4 v = *(const float4*)(in + i * 4);
    ushort4 u;
    u.x = f2bf_bits(v.x); u.y = f2bf_bits(v.y);
    u.z = f2bf_bits(v.z); u.w = f2bf_bits(v.w);
    *(ushort4*)(out + i * 4) = u;
  }
}

// out[c][r] = (bf16) in[r][c], per batch (blockIdx.z)
__global__ __launch_bounds__(256) void transpose_f32_bf16_k(
    const float* __restrict__ in, __bf16* __restrict__ out,
    int R, int C, long long sIn, long long sOut) {
  __shared__ float tile[64][65];
  const float* ib = in + (long long)blockIdx.z * sIn;
  __bf16* ob = out + (long long)blockIdx.z * sOut;
  const int r0 = blockIdx.y * 64, c0 = blockIdx.x * 64;
  const int tr = threadIdx.x >> 6, tc = threadIdx.x & 63;
#pragma unroll
  for (int i = 0; i < 16; ++i) {
    const int rr = tr + i * 4;
    tile[rr][tc] = ib[(long long)(r0 + rr) * C + (c0 + tc)];
  }
  __syncthreads();
#pragma unroll
  for (int i = 0; i < 16; ++i) {
    const int cc = tr + i * 4;
    ob[(long long)(c0 + cc) * R + (r0 + tc)] = (__bf16)tile[tc][cc];
  }
}

__global__ __launch_bounds__(256) void transpose_bf16_k(
    const __bf16* __restrict__ in, __bf16* __restrict__ out,
    int R, int C, long long sIn, long long sOut) {
  __shared__ unsigned short tile[64][66];
  const unsigned short* ib = (const unsigned short*)in + (long long)blockIdx.z * sIn;
  unsigned short* ob = (unsigned short*)out + (long long)blockIdx.z * sOut;
  const int r0 = blockIdx.y * 64, c0 = blockIdx.x * 64;
  const int tr = threadIdx.x >> 6, tc = threadIdx.x & 63;
#pragma unroll
  for (int i = 0; i < 16; ++i) {
    const int rr = tr + i * 4;
    tile[rr][tc] = ib[(long long)(r0 + rr) * C + (c0 + tc)];
  }
  __syncthreads();
#pragma unroll
  for (int i = 0; i < 16; ++i) {
    const int cc = tr + i * 4;
    ob[(long long)(c0 + cc) * R + (r0 + tc)] = tile[tc][cc];
  }
}

// ---------------- GEMM: C = op(A @ Bt^T [+ bias]) ----------------
// A [M][lda] bf16 row-major, Bt [N][ldb] bf16 row-major (i.e. B column-major).
// 256 threads = 4 waves in 2x2; wave tile (BM/2)x(BN/2); BK=32.
template <int BM, int BN, bool OUT_BF16, bool RELU, bool HAS_BIAS>
__global__ __launch_bounds__(256) void gemm_bt(
    const __bf16* __restrict__ A, const __bf16* __restrict__ Bt,
    void* __restrict__ C, const float* __restrict__ bias,
    int Kd, int lda, int ldb, int ldc,
    long long strideA, long long strideB, long long strideC) {
  constexpr int BK = 32;
  constexpr int WM = BM / 2, WN = BN / 2;
  constexpr int FM = WM / 16, FN = WN / 16;
  constexpr int ACH = (BM * BK * 2) / 4096;  // 16B loads per thread for A tile
  constexpr int BCH = (BN * BK * 2) / 4096;
  __shared__ alignas(16) __bf16 Alds[BM * BK];
  __shared__ alignas(16) __bf16 Blds[BN * BK];

  const int t = threadIdx.x;
  const int lane = t & 63;
  const int wave = t >> 6;
  const int wm = (wave >> 1) * WM;
  const int wn = (wave & 1) * WN;
  const int l15 = lane & 15;
  const int l4 = lane >> 4;
  const long long bm0 = (long long)blockIdx.y * BM;
  const long long bn0 = (long long)blockIdx.x * BN;
  const __bf16* Ab = A + (long long)blockIdx.z * strideA;
  const __bf16* Bb = Bt + (long long)blockIdx.z * strideB;

  f32x4 acc[FM][FN];
  const f32x4 zero = {0.f, 0.f, 0.f, 0.f};
#pragma unroll
  for (int i = 0; i < FM; ++i)
#pragma unroll
    for (int j = 0; j < FN; ++j) acc[i][j] = zero;

  for (int kk = 0; kk < Kd; kk += BK) {
#pragma unroll
    for (int c = 0; c < ACH; ++c) {
      const int idx = c * 256 + t;  // row = idx/4, 16B col-chunk = idx%4
      const __bf16* src = Ab + (bm0 + (idx >> 2)) * lda + kk + (idx & 3) * 8;
      async_load16(src, &Alds[idx * 8]);
    }
#pragma unroll
    for (int c = 0; c < BCH; ++c) {
      const int idx = c * 256 + t;
      const __bf16* src = Bb + (bn0 + (idx >> 2)) * ldb + kk + (idx & 3) * 8;
      async_load16(src, &Blds[idx * 8]);
    }
    __syncthreads();  // drains vmcnt(0) before barrier -> LDS valid
    bf16x8 af[FM], bfr[FN];
#pragma unroll
    for (int i = 0; i < FM; ++i)
      af[i] = *(const bf16x8*)&Alds[(wm + i * 16 + l15) * BK + l4 * 8];
#pragma unroll
    for (int j = 0; j < FN; ++j)
      bfr[j] = *(const bf16x8*)&Blds[(wn + j * 16 + l15) * BK + l4 * 8];
#pragma unroll
    for (int i = 0; i < FM; ++i)
#pragma unroll
      for (int j = 0; j < FN; ++j)
        acc[i][j] = __builtin_amdgcn_mfma_f32_16x16x32_bf16(af[i], bfr[j], acc[i][j], 0, 0, 0);
    __syncthreads();
  }

#pragma unroll
  for (int j = 0; j < FN; ++j) {
    const long long col = bn0 + wn + j * 16 + l15;
    const float bv = HAS_BIAS ? bias[col] : 0.0f;
#pragma unroll
    for (int i = 0; i < FM; ++i) {
#pragma unroll
      for (int r = 0; r < 4; ++r) {
        const long long row = bm0 + wm + i * 16 + l4 * 4 + r;  // C/D: col=lane&15, row=(lane>>4)*4+r
        float v = acc[i][j][r] + bv;
        if (RELU) v = fmaxf(v, 0.0f);
        const long long off = (long long)blockIdx.z * strideC + row * ldc + col;
        if (OUT_BF16) ((__bf16*)C)[off] = (__bf16)v;
        else          ((float*)C)[off] = v;
      }
    }
  }
}

// ---------------- softmax over K=256, wave per row ----------------
__global__ __launch_bounds__(256) void softmax_k(const float* __restrict__ logits,
                                                 const float* __restrict__ mask,
                                                 __bf16* __restrict__ S) {
  const int row = blockIdx.x * 4 + (threadIdx.x >> 6);
  const int lane = threadIdx.x & 63;
  const float* lp = logits + (long long)row * 256;
  const float mb = -1e9f * (1.0f - mask[row]);  // matches reference masking semantics
  float v[4];
  float mx = -3.4e38f;
#pragma unroll
  for (int j = 0; j < 4; ++j) {
    v[j] = lp[lane + 64 * j] + mb;
    mx = fmaxf(mx, v[j]);
  }
#pragma unroll
  for (int o = 32; o > 0; o >>= 1) mx = fmaxf(mx, __shfl_xor(mx, o, 64));
  float s = 0.f;
#pragma unroll
  for (int j = 0; j < 4; ++j) {
    v[j] = __expf(v[j] - mx);
    s += v[j];
  }
#pragma unroll
  for (int o = 32; o > 0; o >>= 1) s += __shfl_xor(s, o, 64);
  const float inv = 1.0f / s;
  __bf16* sp = S + (long long)row * 256;
#pragma unroll
  for (int j = 0; j < 4; ++j) sp[lane + 64 * j] = (__bf16)(v[j] * inv);
}

// ---------------- degree renorm ----------------
__global__ __launch_bounds__(256) void rowsum_k(const float* __restrict__ pooled,
                                                float* __restrict__ dinv) {
  const int row = blockIdx.x * 4 + (threadIdx.x >> 6);  // 8*256 rows
  const int lane = threadIdx.x & 63;
  const float* p = pooled + (long long)row * 256;
  float s = p[lane] + p[lane + 64] + p[lane + 128] + p[lane + 192];
#pragma unroll
  for (int o = 32; o > 0; o >>= 1) s += __shfl_xor(s, o, 64);
  if (lane == 0) dinv[row] = rsqrtf(s + 1e-9f);
}

__global__ __launch_bounds__(256) void finalize_k(const float* __restrict__ pooled,
                                                  const float* __restrict__ dinv,
                                                  float* __restrict__ outAdj,
                                                  float* __restrict__ pmask) {
  const long long i = blockIdx.x * 256LL + threadIdx.x;  // 524288 = 8*256*256
  const int c = (int)(i & 255);
  const int r = (int)((i >> 8) & 255);
  const int b = (int)(i >> 16);
  outAdj[i] = pooled[i] * dinv[b * 256 + r] * dinv[b * 256 + c];
  if (i < 2048) pmask[i] = 1.0f;
}

extern "C" void kernel_launch(void* const* d_in, const int* in_sizes, int n_in,
                              void* d_out, int out_size, void* d_ws, size_t ws_size,
                              hipStream_t stream) {
  (void)in_sizes; (void)n_in; (void)out_size; (void)ws_size;
  const float* x    = (const float*)d_in[0];  // [8,2048,512]
  const float* adj  = (const float*)d_in[1];  // [8,2048,2048]
  const float* mask = (const float*)d_in[2];  // [8,2048]
  const float* W1   = (const float*)d_in[3];  // [512,256]
  const float* b1   = (const float*)d_in[4];  // [256]
  const float* W2   = (const float*)d_in[5];  // [256,256]
  const float* b2   = (const float*)d_in[6];  // [256]

  char* ws = (char*)d_ws;
  // workspace layout (bytes); total 134,610,944 (~128.4 MiB)
  __bf16* adjb   = (__bf16*)(ws + 0);           // 67,108,864
  __bf16* xb     = (__bf16*)(ws + 67108864);    // 16,777,216
  float*  logits = (float*)(ws + 67108864);     // reuse xb (dead after G1)
  __bf16* xbT    = (__bf16*)(ws + 83886080);    // 16,777,216
  __bf16* W1T    = (__bf16*)(ws + 100663296);   //    262,144
  __bf16* W2T    = (__bf16*)(ws + 100925440);   //    131,072
  __bf16* h      = (__bf16*)(ws + 101056512);   //  8,388,608
  __bf16* midT   = (__bf16*)(ws + 101056512);   // reuse h (dead after G2)
  __bf16* S      = (__bf16*)(ws + 109445120);   //  8,388,608
  float*  pooled = (float*)(ws + 109445120);    // reuse S (dead after transpose)
  float*  dinv   = (float*)(ws + 111542272);    //      8,192 (inside old S region)
  __bf16* ST     = (__bf16*)(ws + 117833728);   //  8,388,608
  __bf16* mid    = (__bf16*)(ws + 126222336);   //  8,388,608

  float* pfeat  = (float*)d_out;                // [8,256,512]
  float* outAdj = (float*)d_out + 1048576;      // [8,256,256]
  float* pmask  = (float*)d_out + 1572864;      // [8,256]

  // converts
  cvt_f32_bf16_k<<<2048, 256, 0, stream>>>(x, xb, 2097152);
  cvt_f32_bf16_k<<<4096, 256, 0, stream>>>(adj, adjb, 8388608);
  transpose_f32_bf16_k<<<dim3(8, 32, 8), 256, 0, stream>>>(x, xbT, 2048, 512, 1048576, 1048576);
  transpose_f32_bf16_k<<<dim3(4, 8, 1), 256, 0, stream>>>(W1, W1T, 512, 256, 0, 0);
  transpose_f32_bf16_k<<<dim3(4, 4, 1), 256, 0, stream>>>(W2, W2T, 256, 256, 0, 0);

  // G1: h = relu(x @ W1 + b1)   [16384x512]x[512x256]
  gemm_bt<128, 128, true, true, true><<<dim3(2, 128, 1), 256, 0, stream>>>(
      xb, W1T, h, b1, 512, 512, 512, 256, 0, 0, 0);
  // G2: logits = h @ W2 + b2    [16384x256]x[256x256]
  gemm_bt<128, 128, false, false, true><<<dim3(2, 128, 1), 256, 0, stream>>>(
      h, W2T, logits, b2, 256, 256, 256, 256, 0, 0, 0);
  // softmax rows -> S (bf16)
  softmax_k<<<4096, 256, 0, stream>>>(logits, mask, S);
  // S -> ST per batch
  transpose_bf16_k<<<dim3(4, 32, 8), 256, 0, stream>>>(S, ST, 2048, 256, 524288, 524288);
  // G3: mid = adj @ S           per batch [2048x2048]x[2048x256]
  gemm_bt<128, 128, true, false, false><<<dim3(2, 16, 8), 256, 0, stream>>>(
      adjb, ST, mid, nullptr, 2048, 2048, 2048, 256, 4194304, 524288, 524288);
  // mid -> midT per batch
  transpose_bf16_k<<<dim3(4, 32, 8), 256, 0, stream>>>(mid, midT, 2048, 256, 524288, 524288);
  // G4: pooled = S^T @ mid      per batch [256x2048]x[2048x256], f32 out
  gemm_bt<64, 64, false, false, false><<<dim3(4, 4, 8), 256, 0, stream>>>(
      ST, midT, pooled, nullptr, 2048, 2048, 2048, 256, 524288, 524288, 65536);
  // G5: pfeat = S^T @ x         per batch [256x2048]x[2048x512], f32 out -> d_out
  gemm_bt<64, 64, false, false, false><<<dim3(8, 4, 8), 256, 0, stream>>>(
      ST, xbT, pfeat, nullptr, 2048, 2048, 2048, 512, 524288, 1048576, 131072);
  // degree renorm + pmask
  rowsum_k<<<512, 256, 0, stream>>>(pooled, dinv);
  finalize_k<<<2048, 256, 0, stream>>>(pooled, dinv, outAdj, pmask);
}